// Round 5
// baseline (2308.168 us; speedup 1.0000x reference)
//
#include <hip/hip_runtime.h>
#include <math.h>

#define N_NODES 100000
#define N_EDGES 1600000
#define F_IN 32
#define HID 128
#define N_GRAPHS 2048
#define BOND 10
#define SCAN_B 1024
#define N_SCAN_BLKS ((N_NODES + SCAN_B - 1) / SCAN_B)   // 98

// ---- CSR build step 1: in-degree histogram ----
__global__ void deg_kernel(const int* __restrict__ ei, int* __restrict__ deg) {
    int e = blockIdx.x * 256 + threadIdx.x;
    if (e >= N_EDGES) return;
    atomicAdd(&deg[ei[N_EDGES + e]], 1);
}

// ---- CSR build step 2a: per-block exclusive scan of deg ----
__global__ __launch_bounds__(SCAN_B) void scanA(const int* __restrict__ deg,
                                                int* __restrict__ eofs,
                                                int* __restrict__ bsum) {
    __shared__ int s[SCAN_B];
    int tid = threadIdx.x;
    int i = blockIdx.x * SCAN_B + tid;
    int val = (i < N_NODES) ? deg[i] : 0;
    s[tid] = val;
    __syncthreads();
    for (int off = 1; off < SCAN_B; off <<= 1) {
        int t = (tid >= off) ? s[tid - off] : 0;
        __syncthreads();
        s[tid] += t;
        __syncthreads();
    }
    if (i < N_NODES) eofs[i] = s[tid] - val;          // exclusive within block
    if (tid == SCAN_B - 1) bsum[blockIdx.x] = s[tid]; // block total
}

// ---- CSR build step 2b: exclusive scan of the 98 block sums ----
__global__ __launch_bounds__(128) void scanB(const int* __restrict__ bsum,
                                             int* __restrict__ bofs) {
    __shared__ int s[128];
    int tid = threadIdx.x;
    int val = (tid < N_SCAN_BLKS) ? bsum[tid] : 0;
    s[tid] = val;
    __syncthreads();
    for (int off = 1; off < 128; off <<= 1) {
        int t = (tid >= off) ? s[tid - off] : 0;
        __syncthreads();
        s[tid] += t;
        __syncthreads();
    }
    if (tid < N_SCAN_BLKS) bofs[tid] = s[tid] - val;
}

// ---- CSR build step 2c: combine -> global offsets ----
__global__ void scanC(const int* __restrict__ eofs, const int* __restrict__ bofs,
                      int* __restrict__ ofs) {
    int i = blockIdx.x * 256 + threadIdx.x;
    if (i >= N_NODES) return;
    ofs[i] = eofs[i] + bofs[i >> 10];
}

// ---- CSR build step 3 (+ fused bond MLP): fill (src, w) pairs grouped by target ----
__global__ void fill_kernel(const int* __restrict__ ei, const float* __restrict__ ea,
                            const float* __restrict__ bW, const float* __restrict__ bb,
                            const int* __restrict__ ofs, int* __restrict__ cur,
                            int* __restrict__ csr_src, float* __restrict__ csr_w) {
    int e = blockIdx.x * 256 + threadIdx.x;
    if (e >= N_EDGES) return;
    const float* row = ea + (size_t)e * BOND;
    float wv = bb[0];
#pragma unroll
    for (int d = 0; d < BOND; ++d) wv += row[d] * bW[d];
    int t = ei[N_EDGES + e];
    int pos = ofs[t] + atomicAdd(&cur[t], 1);
    csr_src[pos] = ei[e];
    csr_w[pos] = wv;
}

// ---- layer 1: gather agg1 into LDS, then h1 = agg1@rel1^T + b + x@root1^T ----
// 256 thr = 4 waves; 64 rows/block. Gather: 4 lanes/row (8 floats each), edge walk
// unrolled x4 for MLP. GEMM: wave q -> output cols [q*32, q*32+32), K in 2 chunks.
__global__ __launch_bounds__(256, 4) void gemm1_fused(
    const float* __restrict__ x, const float* __restrict__ csr_w,
    const int* __restrict__ csr_src, const int* __restrict__ ofs,
    const int* __restrict__ deg,
    const float* __restrict__ relW, const float* __restrict__ relB,
    const float* __restrict__ rootW, float* __restrict__ h1) {
    __shared__ float Wc[32][HID];        // 16 KB, reloaded per K-chunk
    __shared__ float Ag[64][F_IN + 1];   // 8.25 KB; +1 pad -> (lr+k)%32 banks on read
    int tid = threadIdx.x;
    int lr = tid & 63;
    int q = tid >> 6;                    // wave-uniform output quadrant
    int r = blockIdx.x * 64 + lr;
    bool active = (r < N_NODES);

    // hoist root-term row load: issues early, drains under the gather below
    float rowX[32];
    if (active) {
        const float4* x4 = (const float4*)(x + (size_t)r * F_IN);
#pragma unroll
        for (int i = 0; i < 8; ++i) ((float4*)rowX)[i] = x4[i];
    }

    // ---- gather phase ----
    {
        int gr = blockIdx.x * 64 + (tid >> 2);
        int c = (tid & 3) * 8;
        float a[8];
#pragma unroll
        for (int i = 0; i < 8; ++i) a[i] = 0.0f;
        if (gr < N_NODES) {
            int o = ofs[gr], d = deg[gr];
            int i = 0;
            for (; i + 4 <= d; i += 4) {               // 4 edges in flight
                int s0 = csr_src[o + i],     s1 = csr_src[o + i + 1];
                int s2 = csr_src[o + i + 2], s3 = csr_src[o + i + 3];
                float w0 = csr_w[o + i],     w1 = csr_w[o + i + 1];
                float w2 = csr_w[o + i + 2], w3 = csr_w[o + i + 3];
                const float4* p0 = (const float4*)(x + (size_t)s0 * F_IN + c);
                const float4* p1 = (const float4*)(x + (size_t)s1 * F_IN + c);
                const float4* p2 = (const float4*)(x + (size_t)s2 * F_IN + c);
                const float4* p3 = (const float4*)(x + (size_t)s3 * F_IN + c);
                float4 u0 = p0[0], u1 = p0[1], v0 = p1[0], v1 = p1[1];
                float4 y0 = p2[0], y1 = p2[1], z0 = p3[0], z1 = p3[1];
                a[0] += w0 * u0.x + w1 * v0.x + w2 * y0.x + w3 * z0.x;
                a[1] += w0 * u0.y + w1 * v0.y + w2 * y0.y + w3 * z0.y;
                a[2] += w0 * u0.z + w1 * v0.z + w2 * y0.z + w3 * z0.z;
                a[3] += w0 * u0.w + w1 * v0.w + w2 * y0.w + w3 * z0.w;
                a[4] += w0 * u1.x + w1 * v1.x + w2 * y1.x + w3 * z1.x;
                a[5] += w0 * u1.y + w1 * v1.y + w2 * y1.y + w3 * z1.y;
                a[6] += w0 * u1.z + w1 * v1.z + w2 * y1.z + w3 * z1.z;
                a[7] += w0 * u1.w + w1 * v1.w + w2 * y1.w + w3 * z1.w;
            }
            for (; i < d; ++i) {
                int s0 = csr_src[o + i];
                float w0 = csr_w[o + i];
                const float4* p0 = (const float4*)(x + (size_t)s0 * F_IN + c);
                float4 u0 = p0[0], u1 = p0[1];
                a[0] += w0 * u0.x; a[1] += w0 * u0.y; a[2] += w0 * u0.z; a[3] += w0 * u0.w;
                a[4] += w0 * u1.x; a[5] += w0 * u1.y; a[6] += w0 * u1.z; a[7] += w0 * u1.w;
            }
        }
#pragma unroll
        for (int i = 0; i < 8; ++i) Ag[tid >> 2][c + i] = a[i];
    }

    // ---- GEMM phase ----
    float acc[32];
    if (active) {
#pragma unroll
        for (int j = 0; j < 32; ++j) acc[j] = relB[q * 32 + j];
    }

    for (int kc = 0; kc < 2; ++kc) {     // kc=0: rel1 x Ag ; kc=1: root1 x rowX
        __syncthreads();                 // fences Ag writes (kc=0) / prev compute
        const float* Wsrc = (kc == 0) ? relW : rootW;
        for (int i = tid; i < 32 * HID; i += 256) {
            int k = i >> 7, j = i & 127;
            Wc[k][j] = Wsrc[j * F_IN + k];
        }
        __syncthreads();
        if (active) {
#pragma unroll
            for (int k = 0; k < 32; ++k) {
                float v = (kc == 0) ? Ag[lr][k] : rowX[k];
                const float4* wp = (const float4*)&Wc[k][q * 32];   // wave-uniform bcast
#pragma unroll
                for (int i = 0; i < 8; ++i) {
                    float4 aa = wp[i];
                    acc[i * 4 + 0] += v * aa.x;
                    acc[i * 4 + 1] += v * aa.y;
                    acc[i * 4 + 2] += v * aa.z;
                    acc[i * 4 + 3] += v * aa.w;
                }
            }
        }
    }
    if (!active) return;
    float4* h4 = (float4*)(h1 + (size_t)r * HID + q * 32);
#pragma unroll
    for (int i = 0; i < 8; ++i) h4[i] = ((float4*)acc)[i];
}

// ---- layer 2: gather agg2 (w*relu(h1[src])) into LDS, then
//      h2 = agg2@rel2^T + b + relu(h1)@root2^T, materialized for pooling ----
__global__ __launch_bounds__(256, 3) void gemm2_fused(
    const float* __restrict__ h1, const float* __restrict__ csr_w,
    const int* __restrict__ csr_src, const int* __restrict__ ofs,
    const int* __restrict__ deg,
    const float* __restrict__ relW, const float* __restrict__ relB,
    const float* __restrict__ rootW, float* __restrict__ h2) {
    __shared__ float Wc[32][HID];        // 16 KB, reloaded per K-chunk (8 chunks)
    __shared__ float Ag[64][HID + 1];    // 33 KB, persists across chunks
    int tid = threadIdx.x;
    // ---- gather phase: 4 lanes/row, 32 contiguous feats each, edges unrolled x2 ----
    {
        int gr = blockIdx.x * 64 + (tid >> 2);
        int c = (tid & 3) * 32;
        float a[32];
#pragma unroll
        for (int i = 0; i < 32; ++i) a[i] = 0.0f;
        if (gr < N_NODES) {
            int o = ofs[gr], d = deg[gr];
            int i = 0;
            for (; i + 2 <= d; i += 2) {               // 2 edge rows in flight
                int s0 = csr_src[o + i], s1 = csr_src[o + i + 1];
                float w0 = csr_w[o + i], w1 = csr_w[o + i + 1];
                const float4* p0 = (const float4*)(h1 + (size_t)s0 * HID + c);
                const float4* p1 = (const float4*)(h1 + (size_t)s1 * HID + c);
#pragma unroll
                for (int u = 0; u < 8; ++u) {
                    float4 v0 = p0[u], v1 = p1[u];
                    a[u * 4 + 0] += w0 * fmaxf(v0.x, 0.0f) + w1 * fmaxf(v1.x, 0.0f);
                    a[u * 4 + 1] += w0 * fmaxf(v0.y, 0.0f) + w1 * fmaxf(v1.y, 0.0f);
                    a[u * 4 + 2] += w0 * fmaxf(v0.z, 0.0f) + w1 * fmaxf(v1.z, 0.0f);
                    a[u * 4 + 3] += w0 * fmaxf(v0.w, 0.0f) + w1 * fmaxf(v1.w, 0.0f);
                }
            }
            if (i < d) {
                int s0 = csr_src[o + i];
                float w0 = csr_w[o + i];
                const float4* p0 = (const float4*)(h1 + (size_t)s0 * HID + c);
#pragma unroll
                for (int u = 0; u < 8; ++u) {
                    float4 v0 = p0[u];
                    a[u * 4 + 0] += w0 * fmaxf(v0.x, 0.0f);
                    a[u * 4 + 1] += w0 * fmaxf(v0.y, 0.0f);
                    a[u * 4 + 2] += w0 * fmaxf(v0.z, 0.0f);
                    a[u * 4 + 3] += w0 * fmaxf(v0.w, 0.0f);
                }
            }
        }
#pragma unroll
        for (int i = 0; i < 32; ++i) Ag[tid >> 2][c + i] = a[i];
    }

    // ---- GEMM phase: K=256 in 8 chunks of 32 ----
    int lr = tid & 63;
    int q = tid >> 6;
    int r = blockIdx.x * 64 + lr;
    bool active = (r < N_NODES);

    float acc[32];
    if (active) {
#pragma unroll
        for (int j = 0; j < 32; ++j) acc[j] = relB[q * 32 + j];
    }

    for (int kc = 0; kc < 8; ++kc) {     // kc<4: rel2 x Ag ; kc>=4: root2 x relu(h1 row)
        __syncthreads();                 // first iter also fences Ag writes
        const float* Wsrc = (kc < 4) ? relW : rootW;
        int kb = (kc < 4) ? kc * 32 : (kc - 4) * 32;
        for (int i = tid; i < 32 * HID; i += 256) {
            int k = i >> 7, j = i & 127;
            Wc[k][j] = Wsrc[j * HID + kb + k];
        }
        __syncthreads();
        if (active) {
            float rowv[32];
            if (kc < 4) {
#pragma unroll
                for (int k = 0; k < 32; ++k) rowv[k] = Ag[lr][kc * 32 + k];
            } else {
                const float4* src4 = (const float4*)(h1 + (size_t)r * HID + (kc - 4) * 32);
#pragma unroll
                for (int i = 0; i < 8; ++i) ((float4*)rowv)[i] = src4[i];
#pragma unroll
                for (int i = 0; i < 32; ++i) rowv[i] = fmaxf(rowv[i], 0.0f);
            }
#pragma unroll
            for (int k = 0; k < 32; ++k) {
                float v = rowv[k];
                const float4* wp = (const float4*)&Wc[k][q * 32];
#pragma unroll
                for (int i = 0; i < 8; ++i) {
                    float4 aa = wp[i];
                    acc[i * 4 + 0] += v * aa.x;
                    acc[i * 4 + 1] += v * aa.y;
                    acc[i * 4 + 2] += v * aa.z;
                    acc[i * 4 + 3] += v * aa.w;
                }
            }
        }
    }
    if (!active) return;
    float4* h4 = (float4*)(h2 + (size_t)r * HID + q * 32);
#pragma unroll
    for (int i = 0; i < 8; ++i) h4[i] = ((float4*)acc)[i];
}

// ---- pooling: batch is SORTED -> per-graph block, binary-searched row range.
//      256 threads: tid<128 reduces h1 col j, tid>=128 reduces h2 col j. ----
__global__ __launch_bounds__(256) void pool_kernel(
    const float* __restrict__ h1, const float* __restrict__ h2,
    const int* __restrict__ batch, float* __restrict__ p) {
    __shared__ float smx[256], ssm[256];
    int g = blockIdx.x, tid = threadIdx.x;
    int j = tid & 127;
    const float* h = (tid < 128) ? h1 : h2;
    int lo = 0, hi = N_NODES;
    while (lo < hi) { int m = (lo + hi) >> 1; if (batch[m] < g) lo = m + 1; else hi = m; }
    int s0 = lo;
    hi = N_NODES;
    while (lo < hi) { int m = (lo + hi) >> 1; if (batch[m] <= g) lo = m + 1; else hi = m; }
    int s1 = lo;
    float mx = -INFINITY, sm = 0.0f;
    for (int r = s0; r < s1; ++r) {
        float v = h[(size_t)r * HID + j];
        mx = fmaxf(mx, v); sm += v;
    }
    smx[tid] = mx; ssm[tid] = sm;
    __syncthreads();
    if (tid < 128) {
        float ic = 1.0f / fmaxf((float)(s1 - s0), 1.0f);
        p[(size_t)g * 256 + tid]       = smx[tid] + smx[128 + tid];          // gmp1+gmp2
        p[(size_t)g * 256 + 128 + tid] = (ssm[tid] + ssm[128 + tid]) * ic;   // gap1+gap2
    }
}

// ---- head: z = relu(p @ lin1^T + b1); out = z @ lin2^T + b2 ----
__global__ __launch_bounds__(128) void mlp_kernel(
    const float* __restrict__ p,
    const float* __restrict__ l1W, const float* __restrict__ l1b,
    const float* __restrict__ l2W, const float* __restrict__ l2b,
    float* __restrict__ out) {
    __shared__ float ps[256];
    __shared__ float partial[2];
    int g = blockIdx.x, tid = threadIdx.x;
    ps[tid] = p[(size_t)g * 256 + tid];
    ps[128 + tid] = p[(size_t)g * 256 + 128 + tid];
    __syncthreads();
    float acc = l1b[tid];
    const float* wrow = l1W + (size_t)tid * 256;
#pragma unroll 8
    for (int k = 0; k < 256; k += 4) {
        float4 wv = *(const float4*)(wrow + k);
        acc += ps[k] * wv.x + ps[k + 1] * wv.y + ps[k + 2] * wv.z + ps[k + 3] * wv.w;
    }
    float z = fmaxf(acc, 0.0f) * l2W[tid];
#pragma unroll
    for (int off = 32; off; off >>= 1) z += __shfl_down(z, off);
    if ((tid & 63) == 0) partial[tid >> 6] = z;
    __syncthreads();
    if (tid == 0) out[g] = partial[0] + partial[1] + l2b[0];
}

extern "C" void kernel_launch(void* const* d_in, const int* in_sizes, int n_in,
                              void* d_out, int out_size, void* d_ws, size_t ws_size,
                              hipStream_t stream) {
    const float* x      = (const float*)d_in[0];
    const float* edge_a = (const float*)d_in[1];
    const float* bond_W = (const float*)d_in[2];
    const float* bond_b = (const float*)d_in[3];
    const float* rel1_W = (const float*)d_in[4];
    const float* rel1_b = (const float*)d_in[5];
    const float* root1_W= (const float*)d_in[6];
    const float* rel2_W = (const float*)d_in[7];
    const float* rel2_b = (const float*)d_in[8];
    const float* root2_W= (const float*)d_in[9];
    const float* lin1_W = (const float*)d_in[10];
    const float* lin1_b = (const float*)d_in[11];
    const float* lin2_W = (const float*)d_in[12];
    const float* lin2_b = (const float*)d_in[13];
    const int*   ei     = (const int*)d_in[14];
    const int*   batch  = (const int*)d_in[15];

    float* ws = (float*)d_ws;
    size_t off = 0;
    float* csr_w = ws + off; off += N_EDGES;                 // fully written
    float* h1    = ws + off; off += (size_t)N_NODES * HID;   // fully written
    float* h2    = ws + off; off += (size_t)N_NODES * HID;   // fully written
    float* p     = ws + off; off += (size_t)N_GRAPHS * 256;  // fully written
    int* ideg  = (int*)(ws + off);       // N     -- zeroed below
    int* icur  = ideg + N_NODES;         // N     -- zeroed below
    int* iofs  = icur + N_NODES;         // N     -- fully written
    int* ieofs = iofs + N_NODES;         // N     -- fully written
    int* ibsum = ieofs + N_NODES;        // 128   -- [0,98) written
    int* ibofs = ibsum + 128;            // 128
    int* icsr  = ibofs + 128;            // E     -- fully written

    hipMemsetAsync(ideg, 0, (size_t)2 * N_NODES * sizeof(int), stream);

    deg_kernel<<<(N_EDGES + 255) / 256, 256, 0, stream>>>(ei, ideg);
    scanA<<<N_SCAN_BLKS, SCAN_B, 0, stream>>>(ideg, ieofs, ibsum);
    scanB<<<1, 128, 0, stream>>>(ibsum, ibofs);
    scanC<<<(N_NODES + 255) / 256, 256, 0, stream>>>(ieofs, ibofs, iofs);
    fill_kernel<<<(N_EDGES + 255) / 256, 256, 0, stream>>>(ei, edge_a, bond_W, bond_b,
                                                           iofs, icur, icsr, csr_w);
    gemm1_fused<<<(N_NODES + 63) / 64, 256, 0, stream>>>(x, csr_w, icsr, iofs, ideg,
                                                         rel1_W, rel1_b, root1_W, h1);
    gemm2_fused<<<(N_NODES + 63) / 64, 256, 0, stream>>>(h1, csr_w, icsr, iofs, ideg,
                                                         rel2_W, rel2_b, root2_W, h2);
    pool_kernel<<<N_GRAPHS, 256, 0, stream>>>(h1, h2, batch, p);
    mlp_kernel<<<N_GRAPHS, 128, 0, stream>>>(p, lin1_W, lin1_b, lin2_W, lin2_b, (float*)d_out);
}

// Round 6
// 1731.190 us; speedup vs baseline: 1.3333x; 1.3333x over previous
//
#include <hip/hip_runtime.h>
#include <math.h>

#define N_NODES 100000
#define N_EDGES 1600000
#define F_IN 32
#define HID 128
#define N_GRAPHS 2048
#define BOND 10
#define SCAN_B 1024
#define N_SCAN_BLKS ((N_NODES + SCAN_B - 1) / SCAN_B)   // 98

// ---- CSR build step 1: in-degree histogram ----
__global__ void deg_kernel(const int* __restrict__ ei, int* __restrict__ deg) {
    int e = blockIdx.x * 256 + threadIdx.x;
    if (e >= N_EDGES) return;
    atomicAdd(&deg[ei[N_EDGES + e]], 1);
}

// ---- CSR build step 2a: per-block exclusive scan of deg ----
__global__ __launch_bounds__(SCAN_B) void scanA(const int* __restrict__ deg,
                                                int* __restrict__ eofs,
                                                int* __restrict__ bsum) {
    __shared__ int s[SCAN_B];
    int tid = threadIdx.x;
    int i = blockIdx.x * SCAN_B + tid;
    int val = (i < N_NODES) ? deg[i] : 0;
    s[tid] = val;
    __syncthreads();
    for (int off = 1; off < SCAN_B; off <<= 1) {
        int t = (tid >= off) ? s[tid - off] : 0;
        __syncthreads();
        s[tid] += t;
        __syncthreads();
    }
    if (i < N_NODES) eofs[i] = s[tid] - val;          // exclusive within block
    if (tid == SCAN_B - 1) bsum[blockIdx.x] = s[tid]; // block total
}

// ---- CSR build step 2b: exclusive scan of the 98 block sums ----
__global__ __launch_bounds__(128) void scanB(const int* __restrict__ bsum,
                                             int* __restrict__ bofs) {
    __shared__ int s[128];
    int tid = threadIdx.x;
    int val = (tid < N_SCAN_BLKS) ? bsum[tid] : 0;
    s[tid] = val;
    __syncthreads();
    for (int off = 1; off < 128; off <<= 1) {
        int t = (tid >= off) ? s[tid - off] : 0;
        __syncthreads();
        s[tid] += t;
        __syncthreads();
    }
    if (tid < N_SCAN_BLKS) bofs[tid] = s[tid] - val;
}

// ---- CSR build step 2c: combine -> global offsets ----
__global__ void scanC(const int* __restrict__ eofs, const int* __restrict__ bofs,
                      int* __restrict__ ofs) {
    int i = blockIdx.x * 256 + threadIdx.x;
    if (i >= N_NODES) return;
    ofs[i] = eofs[i] + bofs[i >> 10];
}

// ---- CSR build step 3 (+ fused bond MLP): fill (src, w) pairs grouped by target ----
__global__ void fill_kernel(const int* __restrict__ ei, const float* __restrict__ ea,
                            const float* __restrict__ bW, const float* __restrict__ bb,
                            const int* __restrict__ ofs, int* __restrict__ cur,
                            int* __restrict__ csr_src, float* __restrict__ csr_w) {
    int e = blockIdx.x * 256 + threadIdx.x;
    if (e >= N_EDGES) return;
    const float* row = ea + (size_t)e * BOND;
    float wv = bb[0];
#pragma unroll
    for (int d = 0; d < BOND; ++d) wv += row[d] * bW[d];
    int t = ei[N_EDGES + e];
    int pos = ofs[t] + atomicAdd(&cur[t], 1);
    csr_src[pos] = ei[e];
    csr_w[pos] = wv;
}

// ---- layer 1: gather agg1 into LDS, then h1 = agg1@rel1^T + b + x@root1^T ----
// 256 thr = 4 waves; 64 rows/block. Gather: 4 lanes/row (8 floats each), edge walk
// unrolled x2. GEMM: wave q -> output cols [q*32, q*32+32), K in 2 chunks.
// NOTE: no min-waves bound, no hoisted rowX -- round-5 counters showed
// __launch_bounds__(256,4)+hoist forced VGPR=64 -> 5 GB scratch spill, 1.6 ms.
__global__ __launch_bounds__(256) void gemm1_fused(
    const float* __restrict__ x, const float* __restrict__ csr_w,
    const int* __restrict__ csr_src, const int* __restrict__ ofs,
    const int* __restrict__ deg,
    const float* __restrict__ relW, const float* __restrict__ relB,
    const float* __restrict__ rootW, float* __restrict__ h1) {
    __shared__ float Wc[32][HID];        // 16 KB, reloaded per K-chunk
    __shared__ float Ag[64][F_IN + 1];   // 8.25 KB; +1 pad -> (lr+k)%32 banks on read
    int tid = threadIdx.x;
    // ---- gather phase ----
    {
        int gr = blockIdx.x * 64 + (tid >> 2);
        int c = (tid & 3) * 8;
        float a[8];
#pragma unroll
        for (int i = 0; i < 8; ++i) a[i] = 0.0f;
        if (gr < N_NODES) {
            int o = ofs[gr], d = deg[gr];
            int i = 0;
            for (; i + 2 <= d; i += 2) {               // 2 edges in flight
                int s0 = csr_src[o + i], s1 = csr_src[o + i + 1];
                float w0 = csr_w[o + i], w1 = csr_w[o + i + 1];
                const float4* p0 = (const float4*)(x + (size_t)s0 * F_IN + c);
                const float4* p1 = (const float4*)(x + (size_t)s1 * F_IN + c);
                float4 u0 = p0[0], u1 = p0[1], v0 = p1[0], v1 = p1[1];
                a[0] += w0 * u0.x + w1 * v0.x; a[1] += w0 * u0.y + w1 * v0.y;
                a[2] += w0 * u0.z + w1 * v0.z; a[3] += w0 * u0.w + w1 * v0.w;
                a[4] += w0 * u1.x + w1 * v1.x; a[5] += w0 * u1.y + w1 * v1.y;
                a[6] += w0 * u1.z + w1 * v1.z; a[7] += w0 * u1.w + w1 * v1.w;
            }
            if (i < d) {
                int s0 = csr_src[o + i];
                float w0 = csr_w[o + i];
                const float4* p0 = (const float4*)(x + (size_t)s0 * F_IN + c);
                float4 u0 = p0[0], u1 = p0[1];
                a[0] += w0 * u0.x; a[1] += w0 * u0.y; a[2] += w0 * u0.z; a[3] += w0 * u0.w;
                a[4] += w0 * u1.x; a[5] += w0 * u1.y; a[6] += w0 * u1.z; a[7] += w0 * u1.w;
            }
        }
#pragma unroll
        for (int i = 0; i < 8; ++i) Ag[tid >> 2][c + i] = a[i];
    }

    // ---- GEMM phase ----
    int lr = tid & 63;
    int q = tid >> 6;                    // wave-uniform output quadrant
    int r = blockIdx.x * 64 + lr;
    bool active = (r < N_NODES);

    float rowX[32];
    float acc[32];
    if (active) {
        const float4* x4 = (const float4*)(x + (size_t)r * F_IN);
#pragma unroll
        for (int i = 0; i < 8; ++i) ((float4*)rowX)[i] = x4[i];
#pragma unroll
        for (int j = 0; j < 32; ++j) acc[j] = relB[q * 32 + j];
    }

    for (int kc = 0; kc < 2; ++kc) {     // kc=0: rel1 x Ag ; kc=1: root1 x rowX
        __syncthreads();                 // fences Ag writes (kc=0) / prev compute
        const float* Wsrc = (kc == 0) ? relW : rootW;
        for (int i = tid; i < 32 * HID; i += 256) {
            int k = i >> 7, j = i & 127;
            Wc[k][j] = Wsrc[j * F_IN + k];
        }
        __syncthreads();
        if (active) {
#pragma unroll
            for (int k = 0; k < 32; ++k) {
                float v = (kc == 0) ? Ag[lr][k] : rowX[k];
                const float4* wp = (const float4*)&Wc[k][q * 32];   // wave-uniform bcast
#pragma unroll
                for (int i = 0; i < 8; ++i) {
                    float4 aa = wp[i];
                    acc[i * 4 + 0] += v * aa.x;
                    acc[i * 4 + 1] += v * aa.y;
                    acc[i * 4 + 2] += v * aa.z;
                    acc[i * 4 + 3] += v * aa.w;
                }
            }
        }
    }
    if (!active) return;
    float4* h4 = (float4*)(h1 + (size_t)r * HID + q * 32);
#pragma unroll
    for (int i = 0; i < 8; ++i) h4[i] = ((float4*)acc)[i];
}

// ---- layer 2: gather agg2 (w*relu(h1[src])) into LDS, then
//      h2 = agg2@rel2^T + b + relu(h1)@root2^T, materialized for pooling ----
__global__ __launch_bounds__(256, 3) void gemm2_fused(
    const float* __restrict__ h1, const float* __restrict__ csr_w,
    const int* __restrict__ csr_src, const int* __restrict__ ofs,
    const int* __restrict__ deg,
    const float* __restrict__ relW, const float* __restrict__ relB,
    const float* __restrict__ rootW, float* __restrict__ h2) {
    __shared__ float Wc[32][HID];        // 16 KB, reloaded per K-chunk (8 chunks)
    __shared__ float Ag[64][HID + 1];    // 33 KB, persists across chunks
    int tid = threadIdx.x;
    // ---- gather phase: 4 lanes/row, 32 contiguous feats each, edges unrolled x2 ----
    {
        int gr = blockIdx.x * 64 + (tid >> 2);
        int c = (tid & 3) * 32;
        float a[32];
#pragma unroll
        for (int i = 0; i < 32; ++i) a[i] = 0.0f;
        if (gr < N_NODES) {
            int o = ofs[gr], d = deg[gr];
            int i = 0;
            for (; i + 2 <= d; i += 2) {               // 2 edge rows in flight
                int s0 = csr_src[o + i], s1 = csr_src[o + i + 1];
                float w0 = csr_w[o + i], w1 = csr_w[o + i + 1];
                const float4* p0 = (const float4*)(h1 + (size_t)s0 * HID + c);
                const float4* p1 = (const float4*)(h1 + (size_t)s1 * HID + c);
#pragma unroll
                for (int u = 0; u < 8; ++u) {
                    float4 v0 = p0[u], v1 = p1[u];
                    a[u * 4 + 0] += w0 * fmaxf(v0.x, 0.0f) + w1 * fmaxf(v1.x, 0.0f);
                    a[u * 4 + 1] += w0 * fmaxf(v0.y, 0.0f) + w1 * fmaxf(v1.y, 0.0f);
                    a[u * 4 + 2] += w0 * fmaxf(v0.z, 0.0f) + w1 * fmaxf(v1.z, 0.0f);
                    a[u * 4 + 3] += w0 * fmaxf(v0.w, 0.0f) + w1 * fmaxf(v1.w, 0.0f);
                }
            }
            if (i < d) {
                int s0 = csr_src[o + i];
                float w0 = csr_w[o + i];
                const float4* p0 = (const float4*)(h1 + (size_t)s0 * HID + c);
#pragma unroll
                for (int u = 0; u < 8; ++u) {
                    float4 v0 = p0[u];
                    a[u * 4 + 0] += w0 * fmaxf(v0.x, 0.0f);
                    a[u * 4 + 1] += w0 * fmaxf(v0.y, 0.0f);
                    a[u * 4 + 2] += w0 * fmaxf(v0.z, 0.0f);
                    a[u * 4 + 3] += w0 * fmaxf(v0.w, 0.0f);
                }
            }
        }
#pragma unroll
        for (int i = 0; i < 32; ++i) Ag[tid >> 2][c + i] = a[i];
    }

    // ---- GEMM phase: K=256 in 8 chunks of 32 ----
    int lr = tid & 63;
    int q = tid >> 6;
    int r = blockIdx.x * 64 + lr;
    bool active = (r < N_NODES);

    float acc[32];
    if (active) {
#pragma unroll
        for (int j = 0; j < 32; ++j) acc[j] = relB[q * 32 + j];
    }

    for (int kc = 0; kc < 8; ++kc) {     // kc<4: rel2 x Ag ; kc>=4: root2 x relu(h1 row)
        __syncthreads();                 // first iter also fences Ag writes
        const float* Wsrc = (kc < 4) ? relW : rootW;
        int kb = (kc < 4) ? kc * 32 : (kc - 4) * 32;
        for (int i = tid; i < 32 * HID; i += 256) {
            int k = i >> 7, j = i & 127;
            Wc[k][j] = Wsrc[j * HID + kb + k];
        }
        __syncthreads();
        if (active) {
            float rowv[32];
            if (kc < 4) {
#pragma unroll
                for (int k = 0; k < 32; ++k) rowv[k] = Ag[lr][kc * 32 + k];
            } else {
                const float4* src4 = (const float4*)(h1 + (size_t)r * HID + (kc - 4) * 32);
#pragma unroll
                for (int i = 0; i < 8; ++i) ((float4*)rowv)[i] = src4[i];
#pragma unroll
                for (int i = 0; i < 32; ++i) rowv[i] = fmaxf(rowv[i], 0.0f);
            }
#pragma unroll
            for (int k = 0; k < 32; ++k) {
                float v = rowv[k];
                const float4* wp = (const float4*)&Wc[k][q * 32];
#pragma unroll
                for (int i = 0; i < 8; ++i) {
                    float4 aa = wp[i];
                    acc[i * 4 + 0] += v * aa.x;
                    acc[i * 4 + 1] += v * aa.y;
                    acc[i * 4 + 2] += v * aa.z;
                    acc[i * 4 + 3] += v * aa.w;
                }
            }
        }
    }
    if (!active) return;
    float4* h4 = (float4*)(h2 + (size_t)r * HID + q * 32);
#pragma unroll
    for (int i = 0; i < 8; ++i) h4[i] = ((float4*)acc)[i];
}

// ---- pooling: batch is SORTED -> per-graph block, binary-searched row range.
//      256 threads: tid<128 reduces h1 col j, tid>=128 reduces h2 col j. ----
__global__ __launch_bounds__(256) void pool_kernel(
    const float* __restrict__ h1, const float* __restrict__ h2,
    const int* __restrict__ batch, float* __restrict__ p) {
    __shared__ float smx[256], ssm[256];
    int g = blockIdx.x, tid = threadIdx.x;
    int j = tid & 127;
    const float* h = (tid < 128) ? h1 : h2;
    int lo = 0, hi = N_NODES;
    while (lo < hi) { int m = (lo + hi) >> 1; if (batch[m] < g) lo = m + 1; else hi = m; }
    int s0 = lo;
    hi = N_NODES;
    while (lo < hi) { int m = (lo + hi) >> 1; if (batch[m] <= g) lo = m + 1; else hi = m; }
    int s1 = lo;
    float mx = -INFINITY, sm = 0.0f;
    for (int r = s0; r < s1; ++r) {
        float v = h[(size_t)r * HID + j];
        mx = fmaxf(mx, v); sm += v;
    }
    smx[tid] = mx; ssm[tid] = sm;
    __syncthreads();
    if (tid < 128) {
        float ic = 1.0f / fmaxf((float)(s1 - s0), 1.0f);
        p[(size_t)g * 256 + tid]       = smx[tid] + smx[128 + tid];          // gmp1+gmp2
        p[(size_t)g * 256 + 128 + tid] = (ssm[tid] + ssm[128 + tid]) * ic;   // gap1+gap2
    }
}

// ---- head: z = relu(p @ lin1^T + b1); out = z @ lin2^T + b2 ----
__global__ __launch_bounds__(128) void mlp_kernel(
    const float* __restrict__ p,
    const float* __restrict__ l1W, const float* __restrict__ l1b,
    const float* __restrict__ l2W, const float* __restrict__ l2b,
    float* __restrict__ out) {
    __shared__ float ps[256];
    __shared__ float partial[2];
    int g = blockIdx.x, tid = threadIdx.x;
    ps[tid] = p[(size_t)g * 256 + tid];
    ps[128 + tid] = p[(size_t)g * 256 + 128 + tid];
    __syncthreads();
    float acc = l1b[tid];
    const float* wrow = l1W + (size_t)tid * 256;
#pragma unroll 8
    for (int k = 0; k < 256; k += 4) {
        float4 wv = *(const float4*)(wrow + k);
        acc += ps[k] * wv.x + ps[k + 1] * wv.y + ps[k + 2] * wv.z + ps[k + 3] * wv.w;
    }
    float z = fmaxf(acc, 0.0f) * l2W[tid];
#pragma unroll
    for (int off = 32; off; off >>= 1) z += __shfl_down(z, off);
    if ((tid & 63) == 0) partial[tid >> 6] = z;
    __syncthreads();
    if (tid == 0) out[g] = partial[0] + partial[1] + l2b[0];
}

extern "C" void kernel_launch(void* const* d_in, const int* in_sizes, int n_in,
                              void* d_out, int out_size, void* d_ws, size_t ws_size,
                              hipStream_t stream) {
    const float* x      = (const float*)d_in[0];
    const float* edge_a = (const float*)d_in[1];
    const float* bond_W = (const float*)d_in[2];
    const float* bond_b = (const float*)d_in[3];
    const float* rel1_W = (const float*)d_in[4];
    const float* rel1_b = (const float*)d_in[5];
    const float* root1_W= (const float*)d_in[6];
    const float* rel2_W = (const float*)d_in[7];
    const float* rel2_b = (const float*)d_in[8];
    const float* root2_W= (const float*)d_in[9];
    const float* lin1_W = (const float*)d_in[10];
    const float* lin1_b = (const float*)d_in[11];
    const float* lin2_W = (const float*)d_in[12];
    const float* lin2_b = (const float*)d_in[13];
    const int*   ei     = (const int*)d_in[14];
    const int*   batch  = (const int*)d_in[15];

    float* ws = (float*)d_ws;
    size_t off = 0;
    float* csr_w = ws + off; off += N_EDGES;                 // fully written
    float* h1    = ws + off; off += (size_t)N_NODES * HID;   // fully written
    float* h2    = ws + off; off += (size_t)N_NODES * HID;   // fully written
    float* p     = ws + off; off += (size_t)N_GRAPHS * 256;  // fully written
    int* ideg  = (int*)(ws + off);       // N     -- zeroed below
    int* icur  = ideg + N_NODES;         // N     -- zeroed below
    int* iofs  = icur + N_NODES;         // N     -- fully written
    int* ieofs = iofs + N_NODES;         // N     -- fully written
    int* ibsum = ieofs + N_NODES;        // 128   -- [0,98) written
    int* ibofs = ibsum + 128;            // 128
    int* icsr  = ibofs + 128;            // E     -- fully written

    hipMemsetAsync(ideg, 0, (size_t)2 * N_NODES * sizeof(int), stream);

    deg_kernel<<<(N_EDGES + 255) / 256, 256, 0, stream>>>(ei, ideg);
    scanA<<<N_SCAN_BLKS, SCAN_B, 0, stream>>>(ideg, ieofs, ibsum);
    scanB<<<1, 128, 0, stream>>>(ibsum, ibofs);
    scanC<<<(N_NODES + 255) / 256, 256, 0, stream>>>(ieofs, ibofs, iofs);
    fill_kernel<<<(N_EDGES + 255) / 256, 256, 0, stream>>>(ei, edge_a, bond_W, bond_b,
                                                           iofs, icur, icsr, csr_w);
    gemm1_fused<<<(N_NODES + 63) / 64, 256, 0, stream>>>(x, csr_w, icsr, iofs, ideg,
                                                         rel1_W, rel1_b, root1_W, h1);
    gemm2_fused<<<(N_NODES + 63) / 64, 256, 0, stream>>>(h1, csr_w, icsr, iofs, ideg,
                                                         rel2_W, rel2_b, root2_W, h2);
    pool_kernel<<<N_GRAPHS, 256, 0, stream>>>(h1, h2, batch, p);
    mlp_kernel<<<N_GRAPHS, 128, 0, stream>>>(p, lin1_W, lin1_b, lin2_W, lin2_b, (float*)d_out);
}

// Round 7
// 826.511 us; speedup vs baseline: 2.7927x; 2.0946x over previous
//
#include <hip/hip_runtime.h>
#include <math.h>

#define N_NODES 100000
#define N_EDGES 1600000
#define F_IN 32
#define HID 128
#define N_GRAPHS 2048
#define BOND 10
#define SCAN_B 1024
#define N_SCAN_BLKS ((N_NODES + SCAN_B - 1) / SCAN_B)   // 98

// ---- CSR build step 1: in-degree histogram ----
__global__ void deg_kernel(const int* __restrict__ ei, int* __restrict__ deg) {
    int e = blockIdx.x * 256 + threadIdx.x;
    if (e >= N_EDGES) return;
    atomicAdd(&deg[ei[N_EDGES + e]], 1);
}

// ---- CSR build step 2a: per-block exclusive scan of deg ----
__global__ __launch_bounds__(SCAN_B) void scanA(const int* __restrict__ deg,
                                                int* __restrict__ eofs,
                                                int* __restrict__ bsum) {
    __shared__ int s[SCAN_B];
    int tid = threadIdx.x;
    int i = blockIdx.x * SCAN_B + tid;
    int val = (i < N_NODES) ? deg[i] : 0;
    s[tid] = val;
    __syncthreads();
    for (int off = 1; off < SCAN_B; off <<= 1) {
        int t = (tid >= off) ? s[tid - off] : 0;
        __syncthreads();
        s[tid] += t;
        __syncthreads();
    }
    if (i < N_NODES) eofs[i] = s[tid] - val;          // exclusive within block
    if (tid == SCAN_B - 1) bsum[blockIdx.x] = s[tid]; // block total
}

// ---- CSR build step 2b: exclusive scan of the 98 block sums ----
__global__ __launch_bounds__(128) void scanB(const int* __restrict__ bsum,
                                             int* __restrict__ bofs) {
    __shared__ int s[128];
    int tid = threadIdx.x;
    int val = (tid < N_SCAN_BLKS) ? bsum[tid] : 0;
    s[tid] = val;
    __syncthreads();
    for (int off = 1; off < 128; off <<= 1) {
        int t = (tid >= off) ? s[tid - off] : 0;
        __syncthreads();
        s[tid] += t;
        __syncthreads();
    }
    if (tid < N_SCAN_BLKS) bofs[tid] = s[tid] - val;
}

// ---- CSR build step 2c: combine -> global offsets ----
__global__ void scanC(const int* __restrict__ eofs, const int* __restrict__ bofs,
                      int* __restrict__ ofs) {
    int i = blockIdx.x * 256 + threadIdx.x;
    if (i >= N_NODES) return;
    ofs[i] = eofs[i] + bofs[i >> 10];
}

// ---- CSR build step 3 (+ fused bond MLP): fill (src, w) pairs grouped by target ----
__global__ void fill_kernel(const int* __restrict__ ei, const float* __restrict__ ea,
                            const float* __restrict__ bW, const float* __restrict__ bb,
                            const int* __restrict__ ofs, int* __restrict__ cur,
                            int* __restrict__ csr_src, float* __restrict__ csr_w) {
    int e = blockIdx.x * 256 + threadIdx.x;
    if (e >= N_EDGES) return;
    const float* row = ea + (size_t)e * BOND;
    float wv = bb[0];
#pragma unroll
    for (int d = 0; d < BOND; ++d) wv += row[d] * bW[d];
    int t = ei[N_EDGES + e];
    int pos = ofs[t] + atomicAdd(&cur[t], 1);
    csr_src[pos] = ei[e];
    csr_w[pos] = wv;
}

// ---- layer 1: gather agg1 into LDS, then h1 = agg1@rel1^T + b + x@root1^T ----
// SPILL HISTORY (r5/r6 counters): hoisted rowX / fully-unrolled kc loop merged
// both chunk bodies into one scheduling region -> VGPR demand >256 -> 2-5 GB
// scratch traffic, 1.1-1.6 ms. Fix: clone gemm2's proven shape -- rolled kc loop
// (#pragma unroll 1), per-chunk transient rowv, launch_bounds(256,3).
__global__ __launch_bounds__(256, 3) void gemm1_fused(
    const float* __restrict__ x, const float* __restrict__ csr_w,
    const int* __restrict__ csr_src, const int* __restrict__ ofs,
    const int* __restrict__ deg,
    const float* __restrict__ relW, const float* __restrict__ relB,
    const float* __restrict__ rootW, float* __restrict__ h1) {
    __shared__ float Wc[32][HID];        // 16 KB, reloaded per K-chunk
    __shared__ float Ag[64][F_IN + 1];   // 8.25 KB; +1 pad -> (lr+k)%32 banks on read
    int tid = threadIdx.x;
    // ---- gather phase: 4 lanes/row (8 floats each), edge walk unrolled x2 ----
    {
        int gr = blockIdx.x * 64 + (tid >> 2);
        int c = (tid & 3) * 8;
        float a[8];
#pragma unroll
        for (int i = 0; i < 8; ++i) a[i] = 0.0f;
        if (gr < N_NODES) {
            int o = ofs[gr], d = deg[gr];
            int i = 0;
            for (; i + 2 <= d; i += 2) {               // 2 edges in flight
                int s0 = csr_src[o + i], s1 = csr_src[o + i + 1];
                float w0 = csr_w[o + i], w1 = csr_w[o + i + 1];
                const float4* p0 = (const float4*)(x + (size_t)s0 * F_IN + c);
                const float4* p1 = (const float4*)(x + (size_t)s1 * F_IN + c);
                float4 u0 = p0[0], u1 = p0[1], v0 = p1[0], v1 = p1[1];
                a[0] += w0 * u0.x + w1 * v0.x; a[1] += w0 * u0.y + w1 * v0.y;
                a[2] += w0 * u0.z + w1 * v0.z; a[3] += w0 * u0.w + w1 * v0.w;
                a[4] += w0 * u1.x + w1 * v1.x; a[5] += w0 * u1.y + w1 * v1.y;
                a[6] += w0 * u1.z + w1 * v1.z; a[7] += w0 * u1.w + w1 * v1.w;
            }
            if (i < d) {
                int s0 = csr_src[o + i];
                float w0 = csr_w[o + i];
                const float4* p0 = (const float4*)(x + (size_t)s0 * F_IN + c);
                float4 u0 = p0[0], u1 = p0[1];
                a[0] += w0 * u0.x; a[1] += w0 * u0.y; a[2] += w0 * u0.z; a[3] += w0 * u0.w;
                a[4] += w0 * u1.x; a[5] += w0 * u1.y; a[6] += w0 * u1.z; a[7] += w0 * u1.w;
            }
        }
#pragma unroll
        for (int i = 0; i < 8; ++i) Ag[tid >> 2][c + i] = a[i];
    }

    // ---- GEMM phase: K=64 in 2 rolled chunks of 32 ----
    int lr = tid & 63;
    int q = tid >> 6;                    // wave-uniform output quadrant
    int r = blockIdx.x * 64 + lr;
    bool active = (r < N_NODES);

    float acc[32];
    if (active) {
#pragma unroll
        for (int j = 0; j < 32; ++j) acc[j] = relB[q * 32 + j];
    }

#pragma unroll 1
    for (int kc = 0; kc < 2; ++kc) {     // kc=0: rel1 x Ag ; kc=1: root1 x (x row)
        __syncthreads();                 // fences Ag writes (kc=0) / prev compute
        const float* Wsrc = (kc == 0) ? relW : rootW;
        for (int i = tid; i < 32 * HID; i += 256) {
            int k = i >> 7, j = i & 127;
            Wc[k][j] = Wsrc[j * F_IN + k];
        }
        __syncthreads();
        if (active) {
            float rowv[32];              // transient: lives only within this chunk
            if (kc == 0) {
#pragma unroll
                for (int k = 0; k < 32; ++k) rowv[k] = Ag[lr][k];
            } else {
                const float4* x4 = (const float4*)(x + (size_t)r * F_IN);
#pragma unroll
                for (int i = 0; i < 8; ++i) ((float4*)rowv)[i] = x4[i];
            }
#pragma unroll
            for (int k = 0; k < 32; ++k) {
                float v = rowv[k];
                const float4* wp = (const float4*)&Wc[k][q * 32];   // wave-uniform bcast
#pragma unroll
                for (int i = 0; i < 8; ++i) {
                    float4 aa = wp[i];
                    acc[i * 4 + 0] += v * aa.x;
                    acc[i * 4 + 1] += v * aa.y;
                    acc[i * 4 + 2] += v * aa.z;
                    acc[i * 4 + 3] += v * aa.w;
                }
            }
        }
    }
    if (!active) return;
    float4* h4 = (float4*)(h1 + (size_t)r * HID + q * 32);
#pragma unroll
    for (int i = 0; i < 8; ++i) h4[i] = ((float4*)acc)[i];
}

// ---- layer 2: gather agg2 (w*relu(h1[src])) into LDS, then
//      h2 = agg2@rel2^T + b + relu(h1)@root2^T, materialized for pooling ----
__global__ __launch_bounds__(256, 3) void gemm2_fused(
    const float* __restrict__ h1, const float* __restrict__ csr_w,
    const int* __restrict__ csr_src, const int* __restrict__ ofs,
    const int* __restrict__ deg,
    const float* __restrict__ relW, const float* __restrict__ relB,
    const float* __restrict__ rootW, float* __restrict__ h2) {
    __shared__ float Wc[32][HID];        // 16 KB, reloaded per K-chunk (8 chunks)
    __shared__ float Ag[64][HID + 1];    // 33 KB, persists across chunks
    int tid = threadIdx.x;
    // ---- gather phase: 4 lanes/row, 32 contiguous feats each, edges unrolled x2 ----
    {
        int gr = blockIdx.x * 64 + (tid >> 2);
        int c = (tid & 3) * 32;
        float a[32];
#pragma unroll
        for (int i = 0; i < 32; ++i) a[i] = 0.0f;
        if (gr < N_NODES) {
            int o = ofs[gr], d = deg[gr];
            int i = 0;
            for (; i + 2 <= d; i += 2) {               // 2 edge rows in flight
                int s0 = csr_src[o + i], s1 = csr_src[o + i + 1];
                float w0 = csr_w[o + i], w1 = csr_w[o + i + 1];
                const float4* p0 = (const float4*)(h1 + (size_t)s0 * HID + c);
                const float4* p1 = (const float4*)(h1 + (size_t)s1 * HID + c);
#pragma unroll
                for (int u = 0; u < 8; ++u) {
                    float4 v0 = p0[u], v1 = p1[u];
                    a[u * 4 + 0] += w0 * fmaxf(v0.x, 0.0f) + w1 * fmaxf(v1.x, 0.0f);
                    a[u * 4 + 1] += w0 * fmaxf(v0.y, 0.0f) + w1 * fmaxf(v1.y, 0.0f);
                    a[u * 4 + 2] += w0 * fmaxf(v0.z, 0.0f) + w1 * fmaxf(v1.z, 0.0f);
                    a[u * 4 + 3] += w0 * fmaxf(v0.w, 0.0f) + w1 * fmaxf(v1.w, 0.0f);
                }
            }
            if (i < d) {
                int s0 = csr_src[o + i];
                float w0 = csr_w[o + i];
                const float4* p0 = (const float4*)(h1 + (size_t)s0 * HID + c);
#pragma unroll
                for (int u = 0; u < 8; ++u) {
                    float4 v0 = p0[u];
                    a[u * 4 + 0] += w0 * fmaxf(v0.x, 0.0f);
                    a[u * 4 + 1] += w0 * fmaxf(v0.y, 0.0f);
                    a[u * 4 + 2] += w0 * fmaxf(v0.z, 0.0f);
                    a[u * 4 + 3] += w0 * fmaxf(v0.w, 0.0f);
                }
            }
        }
#pragma unroll
        for (int i = 0; i < 32; ++i) Ag[tid >> 2][c + i] = a[i];
    }

    // ---- GEMM phase: K=256 in 8 rolled chunks of 32 ----
    int lr = tid & 63;
    int q = tid >> 6;
    int r = blockIdx.x * 64 + lr;
    bool active = (r < N_NODES);

    float acc[32];
    if (active) {
#pragma unroll
        for (int j = 0; j < 32; ++j) acc[j] = relB[q * 32 + j];
    }

#pragma unroll 1
    for (int kc = 0; kc < 8; ++kc) {     // kc<4: rel2 x Ag ; kc>=4: root2 x relu(h1 row)
        __syncthreads();                 // first iter also fences Ag writes
        const float* Wsrc = (kc < 4) ? relW : rootW;
        int kb = (kc < 4) ? kc * 32 : (kc - 4) * 32;
        for (int i = tid; i < 32 * HID; i += 256) {
            int k = i >> 7, j = i & 127;
            Wc[k][j] = Wsrc[j * HID + kb + k];
        }
        __syncthreads();
        if (active) {
            float rowv[32];
            if (kc < 4) {
#pragma unroll
                for (int k = 0; k < 32; ++k) rowv[k] = Ag[lr][kc * 32 + k];
            } else {
                const float4* src4 = (const float4*)(h1 + (size_t)r * HID + (kc - 4) * 32);
#pragma unroll
                for (int i = 0; i < 8; ++i) ((float4*)rowv)[i] = src4[i];
#pragma unroll
                for (int i = 0; i < 32; ++i) rowv[i] = fmaxf(rowv[i], 0.0f);
            }
#pragma unroll
            for (int k = 0; k < 32; ++k) {
                float v = rowv[k];
                const float4* wp = (const float4*)&Wc[k][q * 32];
#pragma unroll
                for (int i = 0; i < 8; ++i) {
                    float4 aa = wp[i];
                    acc[i * 4 + 0] += v * aa.x;
                    acc[i * 4 + 1] += v * aa.y;
                    acc[i * 4 + 2] += v * aa.z;
                    acc[i * 4 + 3] += v * aa.w;
                }
            }
        }
    }
    if (!active) return;
    float4* h4 = (float4*)(h2 + (size_t)r * HID + q * 32);
#pragma unroll
    for (int i = 0; i < 8; ++i) h4[i] = ((float4*)acc)[i];
}

// ---- pooling: batch is SORTED -> per-graph block, binary-searched row range.
//      256 threads: tid<128 reduces h1 col j, tid>=128 reduces h2 col j. ----
__global__ __launch_bounds__(256) void pool_kernel(
    const float* __restrict__ h1, const float* __restrict__ h2,
    const int* __restrict__ batch, float* __restrict__ p) {
    __shared__ float smx[256], ssm[256];
    int g = blockIdx.x, tid = threadIdx.x;
    int j = tid & 127;
    const float* h = (tid < 128) ? h1 : h2;
    int lo = 0, hi = N_NODES;
    while (lo < hi) { int m = (lo + hi) >> 1; if (batch[m] < g) lo = m + 1; else hi = m; }
    int s0 = lo;
    hi = N_NODES;
    while (lo < hi) { int m = (lo + hi) >> 1; if (batch[m] <= g) lo = m + 1; else hi = m; }
    int s1 = lo;
    float mx = -INFINITY, sm = 0.0f;
    for (int r = s0; r < s1; ++r) {
        float v = h[(size_t)r * HID + j];
        mx = fmaxf(mx, v); sm += v;
    }
    smx[tid] = mx; ssm[tid] = sm;
    __syncthreads();
    if (tid < 128) {
        float ic = 1.0f / fmaxf((float)(s1 - s0), 1.0f);
        p[(size_t)g * 256 + tid]       = smx[tid] + smx[128 + tid];          // gmp1+gmp2
        p[(size_t)g * 256 + 128 + tid] = (ssm[tid] + ssm[128 + tid]) * ic;   // gap1+gap2
    }
}

// ---- head: z = relu(p @ lin1^T + b1); out = z @ lin2^T + b2 ----
__global__ __launch_bounds__(128) void mlp_kernel(
    const float* __restrict__ p,
    const float* __restrict__ l1W, const float* __restrict__ l1b,
    const float* __restrict__ l2W, const float* __restrict__ l2b,
    float* __restrict__ out) {
    __shared__ float ps[256];
    __shared__ float partial[2];
    int g = blockIdx.x, tid = threadIdx.x;
    ps[tid] = p[(size_t)g * 256 + tid];
    ps[128 + tid] = p[(size_t)g * 256 + 128 + tid];
    __syncthreads();
    float acc = l1b[tid];
    const float* wrow = l1W + (size_t)tid * 256;
#pragma unroll 8
    for (int k = 0; k < 256; k += 4) {
        float4 wv = *(const float4*)(wrow + k);
        acc += ps[k] * wv.x + ps[k + 1] * wv.y + ps[k + 2] * wv.z + ps[k + 3] * wv.w;
    }
    float z = fmaxf(acc, 0.0f) * l2W[tid];
#pragma unroll
    for (int off = 32; off; off >>= 1) z += __shfl_down(z, off);
    if ((tid & 63) == 0) partial[tid >> 6] = z;
    __syncthreads();
    if (tid == 0) out[g] = partial[0] + partial[1] + l2b[0];
}

extern "C" void kernel_launch(void* const* d_in, const int* in_sizes, int n_in,
                              void* d_out, int out_size, void* d_ws, size_t ws_size,
                              hipStream_t stream) {
    const float* x      = (const float*)d_in[0];
    const float* edge_a = (const float*)d_in[1];
    const float* bond_W = (const float*)d_in[2];
    const float* bond_b = (const float*)d_in[3];
    const float* rel1_W = (const float*)d_in[4];
    const float* rel1_b = (const float*)d_in[5];
    const float* root1_W= (const float*)d_in[6];
    const float* rel2_W = (const float*)d_in[7];
    const float* rel2_b = (const float*)d_in[8];
    const float* root2_W= (const float*)d_in[9];
    const float* lin1_W = (const float*)d_in[10];
    const float* lin1_b = (const float*)d_in[11];
    const float* lin2_W = (const float*)d_in[12];
    const float* lin2_b = (const float*)d_in[13];
    const int*   ei     = (const int*)d_in[14];
    const int*   batch  = (const int*)d_in[15];

    float* ws = (float*)d_ws;
    size_t off = 0;
    float* csr_w = ws + off; off += N_EDGES;                 // fully written
    float* h1    = ws + off; off += (size_t)N_NODES * HID;   // fully written
    float* h2    = ws + off; off += (size_t)N_NODES * HID;   // fully written
    float* p     = ws + off; off += (size_t)N_GRAPHS * 256;  // fully written
    int* ideg  = (int*)(ws + off);       // N     -- zeroed below
    int* icur  = ideg + N_NODES;         // N     -- zeroed below
    int* iofs  = icur + N_NODES;         // N     -- fully written
    int* ieofs = iofs + N_NODES;         // N     -- fully written
    int* ibsum = ieofs + N_NODES;        // 128   -- [0,98) written
    int* ibofs = ibsum + 128;            // 128
    int* icsr  = ibofs + 128;            // E     -- fully written

    hipMemsetAsync(ideg, 0, (size_t)2 * N_NODES * sizeof(int), stream);

    deg_kernel<<<(N_EDGES + 255) / 256, 256, 0, stream>>>(ei, ideg);
    scanA<<<N_SCAN_BLKS, SCAN_B, 0, stream>>>(ideg, ieofs, ibsum);
    scanB<<<1, 128, 0, stream>>>(ibsum, ibofs);
    scanC<<<(N_NODES + 255) / 256, 256, 0, stream>>>(ieofs, ibofs, iofs);
    fill_kernel<<<(N_EDGES + 255) / 256, 256, 0, stream>>>(ei, edge_a, bond_W, bond_b,
                                                           iofs, icur, icsr, csr_w);
    gemm1_fused<<<(N_NODES + 63) / 64, 256, 0, stream>>>(x, csr_w, icsr, iofs, ideg,
                                                         rel1_W, rel1_b, root1_W, h1);
    gemm2_fused<<<(N_NODES + 63) / 64, 256, 0, stream>>>(h1, csr_w, icsr, iofs, ideg,
                                                         rel2_W, rel2_b, root2_W, h2);
    pool_kernel<<<N_GRAPHS, 256, 0, stream>>>(h1, h2, batch, p);
    mlp_kernel<<<N_GRAPHS, 128, 0, stream>>>(p, lin1_W, lin1_b, lin2_W, lin2_b, (float*)d_out);
}